// Round 2
// baseline (3963.414 us; speedup 1.0000x reference)
//
#include <hip/hip_runtime.h>

#define NNODES 200000
#define NEDGES 400000
#define FIN    165
#define HID    512

typedef __bf16 bf16_t;
typedef __bf16 bf16x8 __attribute__((ext_vector_type(8)));
typedef float  f32x4  __attribute__((ext_vector_type(4)));
typedef unsigned short su16x8 __attribute__((ext_vector_type(8)));

static __device__ __forceinline__ float bf2f(unsigned short u) {
    unsigned int x = ((unsigned int)u) << 16;
    return __builtin_bit_cast(float, x);
}
static __device__ __forceinline__ unsigned short f2bf(float f) {
    bf16_t h = (bf16_t)f;  // RNE
    return __builtin_bit_cast(unsigned short, h);
}
// packed bf16 atomic add (gfx942+): adds 2 bf16 lanes at a 4B-aligned address
static __device__ __forceinline__ void atom_pk_bf16(unsigned short* addr, unsigned int data) {
    asm volatile("global_atomic_pk_add_bf16 %0, %1, off" :: "v"(addr), "v"(data) : "memory");
}

// ---------------- edge weight kernels ----------------
__global__ void k_deg(const int* __restrict__ src, int* __restrict__ deg, int E) {
    int e = blockIdx.x * 256 + threadIdx.x;
    if (e < E) atomicAdd(&deg[src[e]], 1);
}

__global__ void k_edgew(const int* __restrict__ src, const int* __restrict__ dst,
                        const int* __restrict__ deg, float* __restrict__ w, int E) {
    int e = blockIdx.x * 256 + threadIdx.x;
    if (e < E) {
        int a = deg[src[e]], b = deg[dst[e]];
        float fa = a > 0 ? rsqrtf((float)a) : 0.f;
        float fb = b > 0 ? rsqrtf((float)b) : 0.f;
        w[e] = -fa * fb;
    }
}

// ---------------- propagation layer 1: x (f32, F=165) ----------------
__global__ void k_propx(const float* __restrict__ x, const int* __restrict__ src,
                        const int* __restrict__ dst, const float* __restrict__ w,
                        float* __restrict__ out, int E) {
    int wid  = (blockIdx.x * 256 + threadIdx.x) >> 6;
    int lane = threadIdx.x & 63;
    if (wid >= E) return;
    int s = src[wid], d = dst[wid];
    float we = w[wid];
    const float* xs = x + (long)s * FIN;
    float* od = out + (long)d * FIN;
    #pragma unroll
    for (int f = lane; f < FIN; f += 64)
        unsafeAtomicAdd(&od[f], we * xs[f]);
}

// ---------------- propagation layer 2: h1 (bf16, 512) -> pk-bf16 atomics ----------
__global__ void k_proph(const unsigned short* __restrict__ h, const int* __restrict__ src,
                        const int* __restrict__ dst, const float* __restrict__ w,
                        unsigned short* __restrict__ out, int E) {
    int wid  = (blockIdx.x * 256 + threadIdx.x) >> 6;
    int lane = threadIdx.x & 63;
    if (wid >= E) return;
    int s = src[wid], d = dst[wid];
    float we = w[wid];
    const uint4 v = *reinterpret_cast<const uint4*>(h + (long)s * HID + lane * 8);
    unsigned short* od = out + (long)d * HID + lane * 8;
    unsigned int uu[4] = {v.x, v.y, v.z, v.w};
    #pragma unroll
    for (int i = 0; i < 4; ++i) {
        float f0 = we * bf2f((unsigned short)(uu[i] & 0xffffu));
        float f1 = we * bf2f((unsigned short)(uu[i] >> 16));
        unsigned int pk = ((unsigned int)f2bf(f1) << 16) | (unsigned int)f2bf(f0);
        atom_pk_bf16(od + 2 * i, pk);
    }
}

// ---------------- GEMM1: h1 = relu(x@W1_0 + tx1@W1_1 + b1), bf16 out ----------------
// A1: x f32 [M x 165], A2: tx1 f32 [M x 165]. B: [165 x 512] f32. Tile 128x128, BK=32.
__global__ __launch_bounds__(256, 2)
void k_gemm1(const float* __restrict__ A1, const float* __restrict__ A2,
             const float* __restrict__ B1, const float* __restrict__ B2,
             const float* __restrict__ bias, unsigned short* __restrict__ Cout, int M) {
    constexpr int BK = 32, PADK = 40, K = FIN;
    __shared__ unsigned short Al[128 * PADK];
    __shared__ unsigned short Bl[128 * PADK];

    const int t    = threadIdx.x;
    const int lane = t & 63;
    const int wv   = t >> 6;
    const int wm   = wv >> 1, wn = wv & 1;
    const int m0   = blockIdx.x * 128;
    const int n0   = blockIdx.y * 128;

    f32x4 acc[4][4];
    #pragma unroll
    for (int m = 0; m < 4; ++m)
        #pragma unroll
        for (int n = 0; n < 4; ++n)
            acc[m][n] = (f32x4){0.f, 0.f, 0.f, 0.f};

    constexpr int KT = (K + BK - 1) / BK;
    const int sa_k = t & 31, sa_r = t >> 5;
    const int sb_c = t & 127, sb_kq = (t >> 7) * 16;

    #pragma unroll
    for (int ph = 0; ph < 2; ++ph) {
        const float* Ap = ph ? A2 : A1;
        const float* Bp = ph ? B2 : B1;
        for (int kt = 0; kt < KT; ++kt) {
            const int k0 = kt * BK;
            __syncthreads();
            {   // stage A (f32 -> bf16)
                const int gk = k0 + sa_k;
                const bool kok = gk < K;
                #pragma unroll
                for (int i = 0; i < 16; ++i) {
                    int r = sa_r + 8 * i;
                    int grow = m0 + r;
                    unsigned short v = 0;
                    if (kok && grow < M) v = f2bf(Ap[(long)grow * K + gk]);
                    Al[r * PADK + sa_k] = v;
                }
            }
            {   // stage B transposed -> Bl[col][k]
                __align__(16) unsigned short vals[16];
                #pragma unroll
                for (int i = 0; i < 16; ++i) {
                    int gk = k0 + sb_kq + i;
                    float f = (gk < K) ? Bp[(long)gk * HID + n0 + sb_c] : 0.f;
                    vals[i] = f2bf(f);
                }
                *reinterpret_cast<su16x8*>(&Bl[sb_c * PADK + sb_kq]) =
                    *reinterpret_cast<su16x8*>(&vals[0]);
                *reinterpret_cast<su16x8*>(&Bl[sb_c * PADK + sb_kq + 8]) =
                    *reinterpret_cast<su16x8*>(&vals[8]);
            }
            __syncthreads();
            bf16x8 af[4], bfr[4];
            #pragma unroll
            for (int m = 0; m < 4; ++m) {
                int r = wm * 64 + m * 16 + (lane & 15);
                af[m] = *reinterpret_cast<const bf16x8*>(&Al[r * PADK + (lane >> 4) * 8]);
            }
            #pragma unroll
            for (int n = 0; n < 4; ++n) {
                int c = wn * 64 + n * 16 + (lane & 15);
                bfr[n] = *reinterpret_cast<const bf16x8*>(&Bl[c * PADK + (lane >> 4) * 8]);
            }
            #pragma unroll
            for (int m = 0; m < 4; ++m)
                #pragma unroll
                for (int n = 0; n < 4; ++n)
                    acc[m][n] = __builtin_amdgcn_mfma_f32_16x16x32_bf16(af[m], bfr[n], acc[m][n], 0, 0, 0);
        }
    }

    #pragma unroll
    for (int m = 0; m < 4; ++m) {
        int rbase = m0 + wm * 64 + m * 16 + (lane >> 4) * 4;
        #pragma unroll
        for (int n = 0; n < 4; ++n) {
            int c = n0 + wn * 64 + n * 16 + (lane & 15);
            float bv = bias[c];
            #pragma unroll
            for (int j = 0; j < 4; ++j) {
                int r = rbase + j;
                if (r < M) {
                    float v = acc[m][n][j] + bv;
                    v = v > 0.f ? v : 0.f;
                    Cout[(long)r * HID + c] = f2bf(v);
                }
            }
        }
    }
}

// ---------------- GEMM2 (row-strip, in-place over A2): h2 = relu(h1@W2_0 + p1@W2_1 + b2) ----
// BM=128, BN=512 (full width), BK=32, 512 threads = 8 waves (2x4), wave tile 64x128.
// C may alias A2: all global A2 reads finish (barrier) before epilogue stores.
__global__ __launch_bounds__(512, 1)
void k_gemm2(const unsigned short* __restrict__ A1, const unsigned short* __restrict__ A2,
             const float* __restrict__ B1, const float* __restrict__ B2,
             const float* __restrict__ bias, unsigned short* __restrict__ Cout, int M) {
    constexpr int PADK = 40, K = HID, BK = 32, KT = K / BK;
    __shared__ unsigned short Al[128 * PADK];   // 10240 B
    __shared__ unsigned short Bl[512 * PADK];   // 40960 B

    const int t    = threadIdx.x;
    const int lane = t & 63;
    const int wv   = t >> 6;
    const int wm   = wv >> 2, wn = wv & 3;
    const int m0   = blockIdx.x * 128;

    f32x4 acc[4][8];
    #pragma unroll
    for (int m = 0; m < 4; ++m)
        #pragma unroll
        for (int n = 0; n < 8; ++n)
            acc[m][n] = (f32x4){0.f, 0.f, 0.f, 0.f};

    const int ar = t >> 2, akq = (t & 3) * 8;   // A staging: 1 vec16B per thread
    #pragma unroll
    for (int ph = 0; ph < 2; ++ph) {
        const unsigned short* Ap = ph ? A2 : A1;
        const float*          Bp = ph ? B2 : B1;
        for (int kt = 0; kt < KT; ++kt) {
            const int k0 = kt * BK;
            __syncthreads();
            {   // stage A: rows m0..m0+127, k0..k0+31
                int grow = m0 + ar;
                su16x8 v = {0, 0, 0, 0, 0, 0, 0, 0};
                if (grow < M)
                    v = *reinterpret_cast<const su16x8*>(&Ap[(long)grow * HID + k0 + akq]);
                *reinterpret_cast<su16x8*>(&Al[ar * PADK + akq]) = v;
            }
            {   // stage B transposed: Bl[col=t][k0..k0+31]
                __align__(16) unsigned short vals[32];
                #pragma unroll
                for (int i = 0; i < 32; ++i)
                    vals[i] = f2bf(Bp[(long)(k0 + i) * HID + t]);
                #pragma unroll
                for (int q = 0; q < 4; ++q)
                    *reinterpret_cast<su16x8*>(&Bl[t * PADK + q * 8]) =
                        *reinterpret_cast<su16x8*>(&vals[q * 8]);
            }
            __syncthreads();
            bf16x8 af[4], bfr[8];
            #pragma unroll
            for (int m = 0; m < 4; ++m) {
                int r = wm * 64 + m * 16 + (lane & 15);
                af[m] = *reinterpret_cast<const bf16x8*>(&Al[r * PADK + (lane >> 4) * 8]);
            }
            #pragma unroll
            for (int n = 0; n < 8; ++n) {
                int c = wn * 128 + n * 16 + (lane & 15);
                bfr[n] = *reinterpret_cast<const bf16x8*>(&Bl[c * PADK + (lane >> 4) * 8]);
            }
            #pragma unroll
            for (int m = 0; m < 4; ++m)
                #pragma unroll
                for (int n = 0; n < 8; ++n)
                    acc[m][n] = __builtin_amdgcn_mfma_f32_16x16x32_bf16(af[m], bfr[n], acc[m][n], 0, 0, 0);
        }
    }

    #pragma unroll
    for (int m = 0; m < 4; ++m) {
        int rbase = m0 + wm * 64 + m * 16 + (lane >> 4) * 4;
        #pragma unroll
        for (int n = 0; n < 8; ++n) {
            int c = wn * 128 + n * 16 + (lane & 15);
            float bv = bias[c];
            #pragma unroll
            for (int j = 0; j < 4; ++j) {
                int r = rbase + j;
                if (r < M) {
                    float v = acc[m][n][j] + bv;
                    v = v > 0.f ? v : 0.f;
                    Cout[(long)r * HID + c] = f2bf(v);
                }
            }
        }
    }
}

// ---------------- final linear: out[N x 2] = h2 @ Wl + bl (one wave per row) --------
__global__ void k_final(const unsigned short* __restrict__ h2, const float* __restrict__ Wl,
                        const float* __restrict__ bl, float* __restrict__ out, int M) {
    int wid  = (blockIdx.x * 256 + threadIdx.x) >> 6;
    int lane = threadIdx.x & 63;
    if (wid >= M) return;
    const uint4 v = *reinterpret_cast<const uint4*>(h2 + (long)wid * HID + lane * 8);
    const float4* Wp = reinterpret_cast<const float4*>(Wl + lane * 16);
    float4 w0 = Wp[0], w1 = Wp[1], w2 = Wp[2], w3 = Wp[3];
    float wv[16] = {w0.x, w0.y, w0.z, w0.w, w1.x, w1.y, w1.z, w1.w,
                    w2.x, w2.y, w2.z, w2.w, w3.x, w3.y, w3.z, w3.w};
    unsigned int uu[4] = {v.x, v.y, v.z, v.w};
    float s0 = 0.f, s1 = 0.f;
    #pragma unroll
    for (int j = 0; j < 4; ++j) {
        float f0 = bf2f((unsigned short)(uu[j] & 0xffffu));
        float f1 = bf2f((unsigned short)(uu[j] >> 16));
        s0 += f0 * wv[4 * j + 0];
        s1 += f0 * wv[4 * j + 1];
        s0 += f1 * wv[4 * j + 2];
        s1 += f1 * wv[4 * j + 3];
    }
    #pragma unroll
    for (int off = 32; off; off >>= 1) {
        s0 += __shfl_xor(s0, off, 64);
        s1 += __shfl_xor(s1, off, 64);
    }
    if (lane == 0) {
        out[2 * (long)wid]     = s0 + bl[0];
        out[2 * (long)wid + 1] = s1 + bl[1];
    }
}

extern "C" void kernel_launch(void* const* d_in, const int* in_sizes, int n_in,
                              void* d_out, int out_size, void* d_ws, size_t ws_size,
                              hipStream_t stream) {
    const float* x    = (const float*)d_in[0];
    const int*   ei   = (const int*)d_in[1];
    const float* W1_0 = (const float*)d_in[2];
    const float* W1_1 = (const float*)d_in[3];
    const float* b1   = (const float*)d_in[4];
    const float* W2_0 = (const float*)d_in[5];
    const float* W2_1 = (const float*)d_in[6];
    const float* b2   = (const float*)d_in[7];
    const float* Wl   = (const float*)d_in[8];
    const float* bl   = (const float*)d_in[9];
    const int* src = ei;
    const int* dst = ei + NEDGES;
    float* out = (float*)d_out;

    // workspace layout (~412 MB total)
    char* ws = (char*)d_ws;
    size_t off = 0;
    auto alloc = [&](size_t bytes) -> void* {
        void* p = ws + off;
        off += (bytes + 255) & ~(size_t)255;
        return p;
    };
    const size_t hbytes = (size_t)NNODES * HID * 2;      // 204.8 MB
    int*   deg = (int*)alloc((size_t)NNODES * 4);
    float* w   = (float*)alloc((size_t)NEDGES * 4);
    unsigned short* B1 = (unsigned short*)alloc(hbytes); // h1
    unsigned short* B2 = (unsigned short*)alloc(hbytes); // tx1(f32,132MB) -> p1 -> h2
    if (off > ws_size) return;  // ws too small: leaves out zeroed -> absmax-fail (diagnostic)

    float*          tx1 = (float*)B2;
    unsigned short* p1  = B2;
    unsigned short* h2  = B2;
    unsigned short* h1  = B1;

    hipMemsetAsync(deg, 0, (size_t)NNODES * 4, stream);
    hipMemsetAsync(tx1, 0, (size_t)NNODES * FIN * 4, stream);

    k_deg  <<<(NEDGES + 255) / 256, 256, 0, stream>>>(src, deg, NEDGES);
    k_edgew<<<(NEDGES + 255) / 256, 256, 0, stream>>>(src, dst, deg, w, NEDGES);

    // layer 1: tx1 = prop(x); h1 = relu(x@W1_0 + tx1@W1_1 + b1)
    k_propx<<<NEDGES / 4, 256, 0, stream>>>(x, src, dst, w, tx1, NEDGES);
    dim3 g1((NNODES + 127) / 128, HID / 128);
    k_gemm1<<<g1, 256, 0, stream>>>(x, tx1, W1_0, W1_1, b1, h1, NNODES);

    // layer 2: p1 = prop(h1) (bf16 pk atomics); h2 = relu(h1@W2_0 + p1@W2_1 + b2) in-place
    hipMemsetAsync(p1, 0, hbytes, stream);
    k_proph<<<NEDGES / 4, 256, 0, stream>>>(h1, src, dst, w, p1, NEDGES);
    k_gemm2<<<(NNODES + 127) / 128, 512, 0, stream>>>(h1, p1, W2_0, W2_1, b2, h2, NNODES);

    // final linear
    k_final<<<NNODES / 4, 256, 0, stream>>>(h2, Wl, bl, out, NNODES);
}

// Round 3
// 3279.413 us; speedup vs baseline: 1.2086x; 1.2086x over previous
//
#include <hip/hip_runtime.h>

#define NNODES 200000
#define NEDGES 400000
#define FIN    165
#define K1P    192      // FIN padded to 6 x 32
#define HID    512

typedef __bf16 bf16_t;
typedef __bf16 bf16x8 __attribute__((ext_vector_type(8)));
typedef float  f32x4  __attribute__((ext_vector_type(4)));
typedef unsigned short su16x8 __attribute__((ext_vector_type(8)));
typedef float f32x4u __attribute__((ext_vector_type(4), aligned(4)));

static __device__ __forceinline__ float bf2f(unsigned short u) {
    unsigned int x = ((unsigned int)u) << 16;
    return __builtin_bit_cast(float, x);
}
static __device__ __forceinline__ unsigned short f2bf(float f) {
    bf16_t h = (bf16_t)f;  // RNE
    return __builtin_bit_cast(unsigned short, h);
}
static __device__ __forceinline__ void atom_pk_bf16(unsigned short* addr, unsigned int data) {
    asm volatile("global_atomic_pk_add_bf16 %0, %1, off" :: "v"(addr), "v"(data) : "memory");
}

// ---------------- degree ----------------
__global__ void k_deg(const int* __restrict__ src, int* __restrict__ deg, int E) {
    int e = blockIdx.x * 256 + threadIdx.x;
    if (e < E) atomicAdd(&deg[src[e]], 1);
}

// ---------------- build transposed bf16 B panels (once, tiny) ----------------
__global__ void k_buildB1(const float* __restrict__ W1_0, const float* __restrict__ W1_1,
                          unsigned short* __restrict__ Bct1) {
    int idx = blockIdx.x * 256 + threadIdx.x;   // 1024 * K1P
    if (idx >= 1024 * K1P) return;
    int n = idx / K1P, k = idx % K1P;
    float v = 0.f;
    if (k < FIN) v = (n < HID) ? W1_0[k * HID + n] : W1_1[k * HID + (n - HID)];
    Bct1[idx] = f2bf(v);
}

__global__ void k_buildB2(const float* __restrict__ W2_0, const float* __restrict__ W2_1,
                          unsigned short* __restrict__ Bct2) {
    int idx = blockIdx.x * 256 + threadIdx.x;   // 1024 * 512
    if (idx >= 1024 * HID) return;
    int n = idx >> 9, k = idx & 511;
    float v = (n < HID) ? W2_0[k * HID + n] : W2_1[k * HID + (n - HID)];
    Bct2[idx] = f2bf(v);
}

// ---------------- GEMM: U[:, ooff..ooff+512) = A @ Bct  (raw bf16 out) ----------------
// AK=0: A = x f32 [M x 165], K=192 (zero-padded). AK=1: A = relu(U0 + b1) bf16, K=512.
// BM=128, BN=512, BK=32, 512 threads = 8 waves (2m x 4n), wave tile 64x128.
// AK=1 writes in-place over U: safe (each block reads only its own 128 rows; all
// global A reads precede the last barrier; epilogue writes after it).
template<int AK>
__global__ __launch_bounds__(512, 1)
void k_gemm(const void* __restrict__ Aptr, const unsigned short* __restrict__ Bct,
            const float* __restrict__ bfix, unsigned short* __restrict__ U,
            int n_base, int M) {
    constexpr int K  = AK ? HID : K1P;
    constexpr int KT = K / 32;
    __shared__ unsigned short Al[128 * 32];        // 8 KB,  [row][32k] XOR-swizzled
    __shared__ unsigned short Bpl[4][HID * 8];     // 32 KB, kq-planes of [col][8k]

    const int t    = threadIdx.x;
    const int lane = t & 63;
    const int wv   = t >> 6;
    const int wm   = wv >> 2, wn = wv & 3;
    const int m0   = blockIdx.y * 128;
    const int n0   = blockIdx.x * 512;
    const int ooff = n_base + n0;

    f32x4 acc[4][8];
    #pragma unroll
    for (int m = 0; m < 4; ++m)
        #pragma unroll
        for (int n = 0; n < 8; ++n)
            acc[m][n] = (f32x4){0.f, 0.f, 0.f, 0.f};

    const int srow = t >> 2, sch = t & 3;
    const bool rok = (m0 + srow) < M;

    for (int kt = 0; kt < KT; ++kt) {
        const int k0 = kt * 32;
        __syncthreads();
        {   // ---- stage A (swizzled chunk: ch ^ ((row>>1)&3)) ----
            const int gk = k0 + sch * 8;
            su16x8 av;
            if constexpr (AK == 0) {
                float f[8];
                const float* Ab = (const float*)Aptr + (size_t)(m0 + srow) * FIN + gk;
                if (rok && gk + 8 <= FIN) {
                    f32x4u lo = *(const f32x4u*)Ab;
                    f32x4u hi = *(const f32x4u*)(Ab + 4);
                    f[0]=lo.x; f[1]=lo.y; f[2]=lo.z; f[3]=lo.w;
                    f[4]=hi.x; f[5]=hi.y; f[6]=hi.z; f[7]=hi.w;
                } else {
                    #pragma unroll
                    for (int j = 0; j < 8; ++j)
                        f[j] = (rok && gk + j < FIN) ? Ab[j] : 0.f;
                }
                #pragma unroll
                for (int j = 0; j < 8; ++j) av[j] = f2bf(f[j]);
            } else {
                su16x8 hv = {0,0,0,0,0,0,0,0};
                if (rok)
                    hv = *(const su16x8*)((const unsigned short*)Aptr +
                                          (size_t)(m0 + srow) * 1024 + gk);
                float4 c0 = *(const float4*)(bfix + gk);
                float4 c1 = *(const float4*)(bfix + gk + 4);
                float bb[8] = {c0.x,c0.y,c0.z,c0.w,c1.x,c1.y,c1.z,c1.w};
                #pragma unroll
                for (int j = 0; j < 8; ++j) {
                    float f = bf2f(hv[j]) + bb[j];
                    av[j] = f2bf(f > 0.f ? f : 0.f);
                }
            }
            *(su16x8*)&Al[srow * 32 + 8 * (sch ^ ((srow >> 1) & 3))] = av;
        }
        {   // ---- stage B: thread t = col, 64B contiguous from Bct, 4 kq-planes ----
            const unsigned short* Bb = Bct + (size_t)(n0 + t) * K + k0;
            #pragma unroll
            for (int q = 0; q < 4; ++q)
                *(su16x8*)&Bpl[q][t * 8] = *(const su16x8*)(Bb + q * 8);
        }
        __syncthreads();
        bf16x8 af[4], bfr[8];
        #pragma unroll
        for (int m = 0; m < 4; ++m) {
            int r  = wm * 64 + m * 16 + (lane & 15);
            int kq = lane >> 4;
            af[m] = *(const bf16x8*)&Al[r * 32 + 8 * (kq ^ ((r >> 1) & 3))];
        }
        #pragma unroll
        for (int n = 0; n < 8; ++n) {
            int c = wn * 128 + n * 16 + (lane & 15);
            bfr[n] = *(const bf16x8*)&Bpl[lane >> 4][c * 8];
        }
        #pragma unroll
        for (int m = 0; m < 4; ++m)
            #pragma unroll
            for (int n = 0; n < 8; ++n)
                acc[m][n] = __builtin_amdgcn_mfma_f32_16x16x32_bf16(af[m], bfr[n], acc[m][n], 0, 0, 0);
    }

    // epilogue: raw bf16 (bias/relu applied by consumers)
    #pragma unroll
    for (int m = 0; m < 4; ++m) {
        int rb = m0 + wm * 64 + m * 16 + (lane >> 4) * 4;
        #pragma unroll
        for (int n = 0; n < 8; ++n) {
            int c = ooff + wn * 128 + n * 16 + (lane & 15);
            #pragma unroll
            for (int j = 0; j < 4; ++j) {
                int r = rb + j;
                if (r < M) U[(size_t)r * 1024 + c] = f2bf(acc[m][n][j]);
            }
        }
    }
}

// ---------------- prop-add: U0[dst] += w_e * U1[src]  (pk-bf16 atomics) ----------------
__global__ void k_prop(unsigned short* __restrict__ U, const int* __restrict__ src,
                       const int* __restrict__ dst, const int* __restrict__ deg, int E) {
    int wid  = (blockIdx.x * 256 + threadIdx.x) >> 6;
    int lane = threadIdx.x & 63;
    if (wid >= E) return;
    int s = src[wid], d = dst[wid];
    int da = deg[s], db = deg[d];
    if (da <= 0 || db <= 0) return;
    float we = -rsqrtf((float)da) * rsqrtf((float)db);
    const uint4 v = *(const uint4*)(U + (size_t)s * 1024 + 512 + lane * 8);
    unsigned short* od = U + (size_t)d * 1024 + lane * 8;
    unsigned int uu[4] = {v.x, v.y, v.z, v.w};
    #pragma unroll
    for (int i = 0; i < 4; ++i) {
        float f0 = we * bf2f((unsigned short)(uu[i] & 0xffffu));
        float f1 = we * bf2f((unsigned short)(uu[i] >> 16));
        unsigned int pk = ((unsigned int)f2bf(f1) << 16) | (unsigned int)f2bf(f0);
        atom_pk_bf16(od + 2 * i, pk);
    }
}

// ---------------- final: out = relu(U0 + b2) @ Wl + bl ----------------
__global__ void k_final(const unsigned short* __restrict__ U, const float* __restrict__ b2,
                        const float* __restrict__ Wl, const float* __restrict__ bl,
                        float* __restrict__ out, int M) {
    int wid  = (blockIdx.x * 256 + threadIdx.x) >> 6;
    int lane = threadIdx.x & 63;
    if (wid >= M) return;
    const uint4 v = *(const uint4*)(U + (size_t)wid * 1024 + lane * 8);
    float4 c0 = *(const float4*)(b2 + lane * 8);
    float4 c1 = *(const float4*)(b2 + lane * 8 + 4);
    float bb[8] = {c0.x,c0.y,c0.z,c0.w,c1.x,c1.y,c1.z,c1.w};
    const float4* Wp = reinterpret_cast<const float4*>(Wl + lane * 16);
    float4 w0 = Wp[0], w1 = Wp[1], w2 = Wp[2], w3 = Wp[3];
    float wv[16] = {w0.x, w0.y, w0.z, w0.w, w1.x, w1.y, w1.z, w1.w,
                    w2.x, w2.y, w2.z, w2.w, w3.x, w3.y, w3.z, w3.w};
    unsigned int uu[4] = {v.x, v.y, v.z, v.w};
    float s0 = 0.f, s1 = 0.f;
    #pragma unroll
    for (int j = 0; j < 4; ++j) {
        float f0 = bf2f((unsigned short)(uu[j] & 0xffffu)) + bb[2 * j];
        float f1 = bf2f((unsigned short)(uu[j] >> 16))     + bb[2 * j + 1];
        f0 = f0 > 0.f ? f0 : 0.f;
        f1 = f1 > 0.f ? f1 : 0.f;
        s0 += f0 * wv[4 * j + 0];
        s1 += f0 * wv[4 * j + 1];
        s0 += f1 * wv[4 * j + 2];
        s1 += f1 * wv[4 * j + 3];
    }
    #pragma unroll
    for (int off = 32; off; off >>= 1) {
        s0 += __shfl_xor(s0, off, 64);
        s1 += __shfl_xor(s1, off, 64);
    }
    if (lane == 0) {
        out[2 * (size_t)wid]     = s0 + bl[0];
        out[2 * (size_t)wid + 1] = s1 + bl[1];
    }
}

extern "C" void kernel_launch(void* const* d_in, const int* in_sizes, int n_in,
                              void* d_out, int out_size, void* d_ws, size_t ws_size,
                              hipStream_t stream) {
    const float* x    = (const float*)d_in[0];
    const int*   ei   = (const int*)d_in[1];
    const float* W1_0 = (const float*)d_in[2];
    const float* W1_1 = (const float*)d_in[3];
    const float* b1   = (const float*)d_in[4];
    const float* W2_0 = (const float*)d_in[5];
    const float* W2_1 = (const float*)d_in[6];
    const float* b2   = (const float*)d_in[7];
    const float* Wl   = (const float*)d_in[8];
    const float* bl   = (const float*)d_in[9];
    const int* src = ei;
    const int* dst = ei + NEDGES;
    float* out = (float*)d_out;

    // workspace (~411.8 MB, <= round-2's proven 412.3 MB)
    char* ws = (char*)d_ws;
    size_t off = 0;
    auto alloc = [&](size_t bytes) -> void* {
        void* p = ws + off;
        off += (bytes + 255) & ~(size_t)255;
        return p;
    };
    int*            deg  = (int*)alloc((size_t)NNODES * 4);
    unsigned short* Bct1 = (unsigned short*)alloc((size_t)1024 * K1P * 2);
    unsigned short* Bct2 = (unsigned short*)alloc((size_t)1024 * HID * 2);
    unsigned short* U    = (unsigned short*)alloc((size_t)NNODES * 1024 * 2);
    if (off > ws_size) return;  // diagnostic: zero output -> absmax fail

    hipMemsetAsync(deg, 0, (size_t)NNODES * 4, stream);
    k_deg    <<<(NEDGES + 255) / 256, 256, 0, stream>>>(src, deg, NEDGES);
    k_buildB1<<<(1024 * K1P + 255) / 256, 256, 0, stream>>>(W1_0, W1_1, Bct1);
    k_buildB2<<<(1024 * HID + 255) / 256, 256, 0, stream>>>(W2_0, W2_1, Bct2);

    // layer 1: U = x @ [W1_0|W1_1]; then U0[dst] += w * U1[src]
    k_gemm<0><<<dim3(2, (NNODES + 127) / 128), 512, 0, stream>>>(x, Bct1, b1, U, 0, NNODES);
    k_prop<<<NEDGES / 4, 256, 0, stream>>>(U, src, dst, deg, NEDGES);

    // layer 2: h1 = relu(U0 + b1) on the fly; V1 -> U1 first, then V0 -> U0 (in-place)
    k_gemm<1><<<dim3(1, (NNODES + 127) / 128), 512, 0, stream>>>(U, Bct2 + (size_t)HID * HID, b1, U, 512, NNODES);
    k_gemm<1><<<dim3(1, (NNODES + 127) / 128), 512, 0, stream>>>(U, Bct2, b1, U, 0, NNODES);
    k_prop<<<NEDGES / 4, 256, 0, stream>>>(U, src, dst, deg, NEDGES);

    // out = relu(U0 + b2) @ Wl + bl
    k_final<<<NNODES / 4, 256, 0, stream>>>(U, b2, Wl, bl, out, NNODES);
}

// Round 4
// 1312.933 us; speedup vs baseline: 3.0187x; 2.4978x over previous
//
#include <hip/hip_runtime.h>

#define NNODES 200000
#define NEDGES 400000
#define FIN    165
#define K1P    192      // FIN padded to 6 x 32
#define HID    512
#define NB     ((NNODES + 255) / 256)   // 782 scan blocks

typedef __bf16 bf16_t;
typedef __bf16 bf16x8 __attribute__((ext_vector_type(8)));
typedef float  f32x4  __attribute__((ext_vector_type(4)));
typedef unsigned short su16x8 __attribute__((ext_vector_type(8)));
typedef float f32x4u __attribute__((ext_vector_type(4), aligned(4)));

static __device__ __forceinline__ float bf2f(unsigned short u) {
    unsigned int x = ((unsigned int)u) << 16;
    return __builtin_bit_cast(float, x);
}
static __device__ __forceinline__ unsigned short f2bf(float f) {
    bf16_t h = (bf16_t)f;  // RNE
    return __builtin_bit_cast(unsigned short, h);
}

// ---------------- degree histograms (src for weights, dst for CSR) ----------------
__global__ void k_deg(const int* __restrict__ src, const int* __restrict__ dst,
                      int* __restrict__ deg, int* __restrict__ cnt, int E) {
    int e = blockIdx.x * 256 + threadIdx.x;
    if (e < E) {
        atomicAdd(&deg[src[e]], 1);
        atomicAdd(&cnt[dst[e]], 1);
    }
}

// ---------------- CSR build: 2-level exclusive scan of cnt -> rowptr ----------------
__global__ void k_scan1(int* __restrict__ cnt, int* __restrict__ btot, int n) {
    __shared__ int s[256];
    int i = blockIdx.x * 256 + threadIdx.x;
    int v = (i < n) ? cnt[i] : 0;
    s[threadIdx.x] = v;
    __syncthreads();
    #pragma unroll
    for (int off = 1; off < 256; off <<= 1) {
        int t = (threadIdx.x >= off) ? s[threadIdx.x - off] : 0;
        __syncthreads();
        s[threadIdx.x] += t;
        __syncthreads();
    }
    if (i < n) cnt[i] = s[threadIdx.x] - v;            // exclusive within block
    if (threadIdx.x == 255) btot[blockIdx.x] = s[255]; // block total
}

__global__ void k_scan2(int* __restrict__ btot, int nb) {  // one block of 1024
    __shared__ int s[1024];
    int i = threadIdx.x;
    int v = (i < nb) ? btot[i] : 0;
    s[i] = v;
    __syncthreads();
    #pragma unroll
    for (int off = 1; off < 1024; off <<= 1) {
        int t = (i >= off) ? s[i - off] : 0;
        __syncthreads();
        s[i] += t;
        __syncthreads();
    }
    if (i < nb) btot[i] = s[i] - v;                    // exclusive block offsets
}

__global__ void k_scan3(int* __restrict__ cnt, const int* __restrict__ btot,
                        int* __restrict__ rowptr, int n, int E) {
    int i = blockIdx.x * 256 + threadIdx.x;
    if (i < n) {
        rowptr[i] = cnt[i] + btot[blockIdx.x];
        cnt[i] = 0;                                    // becomes scatter cursor
    }
    if (i == 0) rowptr[n] = E;
}

__global__ void k_scatter(const int* __restrict__ src, const int* __restrict__ dst,
                          const int* __restrict__ rowptr, int* __restrict__ cur,
                          int* __restrict__ esrc, int E) {
    int e = blockIdx.x * 256 + threadIdx.x;
    if (e < E) {
        int d = dst[e];
        int pos = rowptr[d] + atomicAdd(&cur[d], 1);
        esrc[pos] = src[e];
    }
}

// ---------------- build transposed bf16 B panels (once, tiny) ----------------
__global__ void k_buildB1(const float* __restrict__ W1_0, const float* __restrict__ W1_1,
                          unsigned short* __restrict__ Bct1) {
    int idx = blockIdx.x * 256 + threadIdx.x;   // 1024 * K1P
    if (idx >= 1024 * K1P) return;
    int n = idx / K1P, k = idx % K1P;
    float v = 0.f;
    if (k < FIN) v = (n < HID) ? W1_0[k * HID + n] : W1_1[k * HID + (n - HID)];
    Bct1[idx] = f2bf(v);
}

__global__ void k_buildB2(const float* __restrict__ W2_0, const float* __restrict__ W2_1,
                          unsigned short* __restrict__ Bct2) {
    int idx = blockIdx.x * 256 + threadIdx.x;   // 1024 * 512
    if (idx >= 1024 * HID) return;
    int n = idx >> 9, k = idx & 511;
    float v = (n < HID) ? W2_0[k * HID + n] : W2_1[k * HID + (n - HID)];
    Bct2[idx] = f2bf(v);
}

// ---------------- GEMM: U[:, ooff..ooff+512) = A @ Bct  (raw bf16 out) ----------------
template<int AK>
__global__ __launch_bounds__(512, 1)
void k_gemm(const void* __restrict__ Aptr, const unsigned short* __restrict__ Bct,
            const float* __restrict__ bfix, unsigned short* __restrict__ U,
            int n_base, int M) {
    constexpr int K  = AK ? HID : K1P;
    constexpr int KT = K / 32;
    __shared__ unsigned short Al[128 * 32];        // 8 KB,  [row][32k] XOR-swizzled
    __shared__ unsigned short Bpl[4][HID * 8];     // 32 KB, kq-planes of [col][8k]

    const int t    = threadIdx.x;
    const int lane = t & 63;
    const int wv   = t >> 6;
    const int wm   = wv >> 2, wn = wv & 3;
    const int m0   = blockIdx.y * 128;
    const int n0   = blockIdx.x * 512;
    const int ooff = n_base + n0;

    f32x4 acc[4][8];
    #pragma unroll
    for (int m = 0; m < 4; ++m)
        #pragma unroll
        for (int n = 0; n < 8; ++n)
            acc[m][n] = (f32x4){0.f, 0.f, 0.f, 0.f};

    const int srow = t >> 2, sch = t & 3;
    const bool rok = (m0 + srow) < M;

    for (int kt = 0; kt < KT; ++kt) {
        const int k0 = kt * 32;
        __syncthreads();
        {   // ---- stage A (swizzled chunk: ch ^ ((row>>1)&3)) ----
            const int gk = k0 + sch * 8;
            su16x8 av;
            if constexpr (AK == 0) {
                float f[8];
                const float* Ab = (const float*)Aptr + (size_t)(m0 + srow) * FIN + gk;
                if (rok && gk + 8 <= FIN) {
                    f32x4u lo = *(const f32x4u*)Ab;
                    f32x4u hi = *(const f32x4u*)(Ab + 4);
                    f[0]=lo.x; f[1]=lo.y; f[2]=lo.z; f[3]=lo.w;
                    f[4]=hi.x; f[5]=hi.y; f[6]=hi.z; f[7]=hi.w;
                } else {
                    #pragma unroll
                    for (int j = 0; j < 8; ++j)
                        f[j] = (rok && gk + j < FIN) ? Ab[j] : 0.f;
                }
                #pragma unroll
                for (int j = 0; j < 8; ++j) av[j] = f2bf(f[j]);
            } else {
                su16x8 hv = {0,0,0,0,0,0,0,0};
                if (rok)
                    hv = *(const su16x8*)((const unsigned short*)Aptr +
                                          (size_t)(m0 + srow) * 1024 + gk);
                float4 c0 = *(const float4*)(bfix + gk);
                float4 c1 = *(const float4*)(bfix + gk + 4);
                float bb[8] = {c0.x,c0.y,c0.z,c0.w,c1.x,c1.y,c1.z,c1.w};
                #pragma unroll
                for (int j = 0; j < 8; ++j) {
                    float f = bf2f(hv[j]) + bb[j];
                    av[j] = f2bf(f > 0.f ? f : 0.f);
                }
            }
            *(su16x8*)&Al[srow * 32 + 8 * (sch ^ ((srow >> 1) & 3))] = av;
        }
        {   // ---- stage B: thread t = col, 64B contiguous from Bct, 4 kq-planes ----
            const unsigned short* Bb = Bct + (size_t)(n0 + t) * K + k0;
            #pragma unroll
            for (int q = 0; q < 4; ++q)
                *(su16x8*)&Bpl[q][t * 8] = *(const su16x8*)(Bb + q * 8);
        }
        __syncthreads();
        bf16x8 af[4], bfr[8];
        #pragma unroll
        for (int m = 0; m < 4; ++m) {
            int r  = wm * 64 + m * 16 + (lane & 15);
            int kq = lane >> 4;
            af[m] = *(const bf16x8*)&Al[r * 32 + 8 * (kq ^ ((r >> 1) & 3))];
        }
        #pragma unroll
        for (int n = 0; n < 8; ++n) {
            int c = wn * 128 + n * 16 + (lane & 15);
            bfr[n] = *(const bf16x8*)&Bpl[lane >> 4][c * 8];
        }
        #pragma unroll
        for (int m = 0; m < 4; ++m)
            #pragma unroll
            for (int n = 0; n < 8; ++n)
                acc[m][n] = __builtin_amdgcn_mfma_f32_16x16x32_bf16(af[m], bfr[n], acc[m][n], 0, 0, 0);
    }

    #pragma unroll
    for (int m = 0; m < 4; ++m) {
        int rb = m0 + wm * 64 + m * 16 + (lane >> 4) * 4;
        #pragma unroll
        for (int n = 0; n < 8; ++n) {
            int c = ooff + wn * 128 + n * 16 + (lane & 15);
            #pragma unroll
            for (int j = 0; j < 4; ++j) {
                int r = rb + j;
                if (r < M) U[(size_t)r * 1024 + c] = f2bf(acc[m][n][j]);
            }
        }
    }
}

// ---------------- aggr: U0[d] += sum_e w_e * U1[src_e]  (CSR, one wave/node, f32 acc) ----
__global__ void k_aggr(unsigned short* U, const int* __restrict__ rowptr,
                       const int* __restrict__ esrc, const int* __restrict__ deg, int M) {
    int wid  = (blockIdx.x * 256 + threadIdx.x) >> 6;
    int lane = threadIdx.x & 63;
    if (wid >= M) return;
    int e0 = rowptr[wid], e1 = rowptr[wid + 1];

    unsigned short* u0 = U + (size_t)wid * 1024 + lane * 8;
    uint4 v0 = *(const uint4*)u0;
    unsigned int a0[4] = {v0.x, v0.y, v0.z, v0.w};
    float acc[8];
    #pragma unroll
    for (int i = 0; i < 4; ++i) {
        acc[2 * i]     = bf2f((unsigned short)(a0[i] & 0xffffu));
        acc[2 * i + 1] = bf2f((unsigned short)(a0[i] >> 16));
    }
    if (e0 == e1) return;  // row unchanged (bit-identical round trip anyway)

    int dd = deg[wid];
    float dr = dd > 0 ? rsqrtf((float)dd) : 0.f;
    for (int e = e0; e < e1; ++e) {
        int s = esrc[e];
        float we = -dr * rsqrtf((float)deg[s]);   // deg[s] >= 1 by construction
        const uint4 v = *(const uint4*)(U + (size_t)s * 1024 + 512 + lane * 8);
        unsigned int uu[4] = {v.x, v.y, v.z, v.w};
        #pragma unroll
        for (int i = 0; i < 4; ++i) {
            acc[2 * i]     += we * bf2f((unsigned short)(uu[i] & 0xffffu));
            acc[2 * i + 1] += we * bf2f((unsigned short)(uu[i] >> 16));
        }
    }
    uint4 w4;
    unsigned int* wo = (unsigned int*)&w4;
    #pragma unroll
    for (int i = 0; i < 4; ++i)
        wo[i] = ((unsigned int)f2bf(acc[2 * i + 1]) << 16) | (unsigned int)f2bf(acc[2 * i]);
    *(uint4*)u0 = w4;
}

// ---------------- final: out = relu(U0 + b2) @ Wl + bl ----------------
__global__ void k_final(const unsigned short* __restrict__ U, const float* __restrict__ b2,
                        const float* __restrict__ Wl, const float* __restrict__ bl,
                        float* __restrict__ out, int M) {
    int wid  = (blockIdx.x * 256 + threadIdx.x) >> 6;
    int lane = threadIdx.x & 63;
    if (wid >= M) return;
    const uint4 v = *(const uint4*)(U + (size_t)wid * 1024 + lane * 8);
    float4 c0 = *(const float4*)(b2 + lane * 8);
    float4 c1 = *(const float4*)(b2 + lane * 8 + 4);
    float bb[8] = {c0.x,c0.y,c0.z,c0.w,c1.x,c1.y,c1.z,c1.w};
    const float4* Wp = reinterpret_cast<const float4*>(Wl + lane * 16);
    float4 w0 = Wp[0], w1 = Wp[1], w2 = Wp[2], w3 = Wp[3];
    float wv[16] = {w0.x, w0.y, w0.z, w0.w, w1.x, w1.y, w1.z, w1.w,
                    w2.x, w2.y, w2.z, w2.w, w3.x, w3.y, w3.z, w3.w};
    unsigned int uu[4] = {v.x, v.y, v.z, v.w};
    float s0 = 0.f, s1 = 0.f;
    #pragma unroll
    for (int j = 0; j < 4; ++j) {
        float f0 = bf2f((unsigned short)(uu[j] & 0xffffu)) + bb[2 * j];
        float f1 = bf2f((unsigned short)(uu[j] >> 16))     + bb[2 * j + 1];
        f0 = f0 > 0.f ? f0 : 0.f;
        f1 = f1 > 0.f ? f1 : 0.f;
        s0 += f0 * wv[4 * j + 0];
        s1 += f0 * wv[4 * j + 1];
        s0 += f1 * wv[4 * j + 2];
        s1 += f1 * wv[4 * j + 3];
    }
    #pragma unroll
    for (int off = 32; off; off >>= 1) {
        s0 += __shfl_xor(s0, off, 64);
        s1 += __shfl_xor(s1, off, 64);
    }
    if (lane == 0) {
        out[2 * (size_t)wid]     = s0 + bl[0];
        out[2 * (size_t)wid + 1] = s1 + bl[1];
    }
}

extern "C" void kernel_launch(void* const* d_in, const int* in_sizes, int n_in,
                              void* d_out, int out_size, void* d_ws, size_t ws_size,
                              hipStream_t stream) {
    const float* x    = (const float*)d_in[0];
    const int*   ei   = (const int*)d_in[1];
    const float* W1_0 = (const float*)d_in[2];
    const float* W1_1 = (const float*)d_in[3];
    const float* b1   = (const float*)d_in[4];
    const float* W2_0 = (const float*)d_in[5];
    const float* W2_1 = (const float*)d_in[6];
    const float* b2   = (const float*)d_in[7];
    const float* Wl   = (const float*)d_in[8];
    const float* bl   = (const float*)d_in[9];
    const int* src = ei;
    const int* dst = ei + NEDGES;
    float* out = (float*)d_out;

    char* ws = (char*)d_ws;
    size_t off = 0;
    auto alloc = [&](size_t bytes) -> void* {
        void* p = ws + off;
        off += (bytes + 255) & ~(size_t)255;
        return p;
    };
    int*            deg    = (int*)alloc((size_t)NNODES * 4);
    int*            cnt    = (int*)alloc((size_t)NNODES * 4);   // counts -> scan -> cursor
    int*            rowptr = (int*)alloc((size_t)(NNODES + 1) * 4);
    int*            btot   = (int*)alloc((size_t)NB * 4);
    unsigned short* Bct1   = (unsigned short*)alloc((size_t)1024 * K1P * 2);
    unsigned short* Bct2   = (unsigned short*)alloc((size_t)1024 * HID * 2);
    unsigned short* U      = (unsigned short*)alloc((size_t)NNODES * 1024 * 2);
    // esrc: 1.6 MB. Prefer ws; fall back to d_out (dead until k_final, same 1.6 MB).
    int* esrc;
    if (off + (size_t)NEDGES * 4 <= ws_size) esrc = (int*)alloc((size_t)NEDGES * 4);
    else                                     esrc = (int*)d_out;

    hipMemsetAsync(deg, 0, (size_t)NNODES * 4, stream);
    hipMemsetAsync(cnt, 0, (size_t)NNODES * 4, stream);

    // CSR build + weights
    k_deg    <<<(NEDGES + 255) / 256, 256, 0, stream>>>(src, dst, deg, cnt, NEDGES);
    k_scan1  <<<NB, 256, 0, stream>>>(cnt, btot, NNODES);
    k_scan2  <<<1, 1024, 0, stream>>>(btot, NB);
    k_scan3  <<<NB, 256, 0, stream>>>(cnt, btot, rowptr, NNODES, NEDGES);
    k_scatter<<<(NEDGES + 255) / 256, 256, 0, stream>>>(src, dst, rowptr, cnt, esrc, NEDGES);

    k_buildB1<<<(1024 * K1P + 255) / 256, 256, 0, stream>>>(W1_0, W1_1, Bct1);
    k_buildB2<<<(1024 * HID + 255) / 256, 256, 0, stream>>>(W2_0, W2_1, Bct2);

    // layer 1: U = x @ [W1_0|W1_1]; then U0[d] += w * U1[src] (CSR gather)
    k_gemm<0><<<dim3(2, (NNODES + 127) / 128), 512, 0, stream>>>(x, Bct1, b1, U, 0, NNODES);
    k_aggr<<<NNODES / 4, 256, 0, stream>>>(U, rowptr, esrc, deg, NNODES);

    // layer 2: h1 = relu(U0 + b1) on the fly; U1 <- h1@W2_1, then U0 <- h1@W2_0 (in-place)
    k_gemm<1><<<dim3(1, (NNODES + 127) / 128), 512, 0, stream>>>(U, Bct2 + (size_t)HID * HID, b1, U, 512, NNODES);
    k_gemm<1><<<dim3(1, (NNODES + 127) / 128), 512, 0, stream>>>(U, Bct2, b1, U, 0, NNODES);
    k_aggr<<<NNODES / 4, 256, 0, stream>>>(U, rowptr, esrc, deg, NNODES);

    // out = relu(U0 + b2) @ Wl + bl
    k_final<<<NNODES / 4, 256, 0, stream>>>(U, b2, Wl, bl, out, NNODES);
}

// Round 5
// 1274.945 us; speedup vs baseline: 3.1087x; 1.0298x over previous
//
#include <hip/hip_runtime.h>

#define NNODES 200000
#define NEDGES 400000
#define FIN    165
#define K1P    192      // FIN padded to 6 x 32
#define HID    512
#define NB     ((NNODES + 255) / 256)   // 782 scan blocks

typedef __bf16 bf16_t;
typedef __bf16 bf16x8 __attribute__((ext_vector_type(8)));
typedef float  f32x4  __attribute__((ext_vector_type(4)));
typedef unsigned short su16x8 __attribute__((ext_vector_type(8)));
typedef float f32x4u __attribute__((ext_vector_type(4), aligned(4)));

static __device__ __forceinline__ float bf2f(unsigned short u) {
    unsigned int x = ((unsigned int)u) << 16;
    return __builtin_bit_cast(float, x);
}
static __device__ __forceinline__ unsigned short f2bf(float f) {
    bf16_t h = (bf16_t)f;  // RNE
    return __builtin_bit_cast(unsigned short, h);
}
// async global->LDS, 16B per lane. LDS dest must be wave-uniform base + lane*16.
static __device__ __forceinline__ void gl_lds16(const void* g, void* l) {
    __builtin_amdgcn_global_load_lds(
        (const __attribute__((address_space(1))) unsigned int*)g,
        (__attribute__((address_space(3))) unsigned int*)l, 16, 0, 0);
}

// ---------------- degree histograms (src for weights, dst for CSR) ----------------
__global__ void k_deg(const int* __restrict__ src, const int* __restrict__ dst,
                      int* __restrict__ deg, int* __restrict__ cnt, int E) {
    int e = blockIdx.x * 256 + threadIdx.x;
    if (e < E) {
        atomicAdd(&deg[src[e]], 1);
        atomicAdd(&cnt[dst[e]], 1);
    }
}

// ---------------- CSR build: 2-level exclusive scan of cnt -> rowptr ----------------
__global__ void k_scan1(int* __restrict__ cnt, int* __restrict__ btot, int n) {
    __shared__ int s[256];
    int i = blockIdx.x * 256 + threadIdx.x;
    int v = (i < n) ? cnt[i] : 0;
    s[threadIdx.x] = v;
    __syncthreads();
    #pragma unroll
    for (int off = 1; off < 256; off <<= 1) {
        int t = (threadIdx.x >= off) ? s[threadIdx.x - off] : 0;
        __syncthreads();
        s[threadIdx.x] += t;
        __syncthreads();
    }
    if (i < n) cnt[i] = s[threadIdx.x] - v;
    if (threadIdx.x == 255) btot[blockIdx.x] = s[255];
}

__global__ void k_scan2(int* __restrict__ btot, int nb) {  // one block of 1024
    __shared__ int s[1024];
    int i = threadIdx.x;
    int v = (i < nb) ? btot[i] : 0;
    s[i] = v;
    __syncthreads();
    #pragma unroll
    for (int off = 1; off < 1024; off <<= 1) {
        int t = (i >= off) ? s[i - off] : 0;
        __syncthreads();
        s[i] += t;
        __syncthreads();
    }
    if (i < nb) btot[i] = s[i] - v;
}

__global__ void k_scan3(int* __restrict__ cnt, const int* __restrict__ btot,
                        int* __restrict__ rowptr, int n, int E) {
    int i = blockIdx.x * 256 + threadIdx.x;
    if (i < n) {
        rowptr[i] = cnt[i] + btot[blockIdx.x];
        cnt[i] = 0;
    }
    if (i == 0) rowptr[n] = E;
}

__global__ void k_scatter(const int* __restrict__ src, const int* __restrict__ dst,
                          const int* __restrict__ rowptr, int* __restrict__ cur,
                          int* __restrict__ esrc, int E) {
    int e = blockIdx.x * 256 + threadIdx.x;
    if (e < E) {
        int d = dst[e];
        int pos = rowptr[d] + atomicAdd(&cur[d], 1);
        esrc[pos] = src[e];
    }
}

// ---------------- build transposed bf16 B panels ----------------
__global__ void k_buildB1(const float* __restrict__ W1_0, const float* __restrict__ W1_1,
                          unsigned short* __restrict__ Bct1) {
    int idx = blockIdx.x * 256 + threadIdx.x;   // 1024 * K1P
    if (idx >= 1024 * K1P) return;
    int n = idx / K1P, k = idx % K1P;
    float v = 0.f;
    if (k < FIN) v = (n < HID) ? W1_0[k * HID + n] : W1_1[k * HID + (n - HID)];
    Bct1[idx] = f2bf(v);
}

__global__ void k_buildB2(const float* __restrict__ W2_0, const float* __restrict__ W2_1,
                          unsigned short* __restrict__ Bct2) {
    int idx = blockIdx.x * 256 + threadIdx.x;   // 1024 * 512
    if (idx >= 1024 * HID) return;
    int n = idx >> 9, k = idx & 511;
    float v = (n < HID) ? W2_0[k * HID + n] : W2_1[k * HID + (n - HID)];
    Bct2[idx] = f2bf(v);
}

// ---------------- GEMM0: U = x @ Bct1 (f32 A, reg-staged; proven round-4 kernel) ----------
__global__ __launch_bounds__(512, 1)
void k_gemm0(const float* __restrict__ Aptr, const unsigned short* __restrict__ Bct,
             unsigned short* __restrict__ U, int M) {
    constexpr int K  = K1P;
    constexpr int KT = K / 32;
    __shared__ unsigned short Al[128 * 32];
    __shared__ unsigned short Bpl[4][HID * 8];

    const int t    = threadIdx.x;
    const int lane = t & 63;
    const int wv   = t >> 6;
    const int wm   = wv >> 2, wn = wv & 3;
    const int m0   = blockIdx.y * 128;
    const int n0   = blockIdx.x * 512;

    f32x4 acc[4][8];
    #pragma unroll
    for (int m = 0; m < 4; ++m)
        #pragma unroll
        for (int n = 0; n < 8; ++n)
            acc[m][n] = (f32x4){0.f, 0.f, 0.f, 0.f};

    const int srow = t >> 2, sch = t & 3;
    const bool rok = (m0 + srow) < M;

    for (int kt = 0; kt < KT; ++kt) {
        const int k0 = kt * 32;
        __syncthreads();
        {
            const int gk = k0 + sch * 8;
            su16x8 av;
            float f[8];
            const float* Ab = Aptr + (size_t)(m0 + srow) * FIN + gk;
            if (rok && gk + 8 <= FIN) {
                f32x4u lo = *(const f32x4u*)Ab;
                f32x4u hi = *(const f32x4u*)(Ab + 4);
                f[0]=lo.x; f[1]=lo.y; f[2]=lo.z; f[3]=lo.w;
                f[4]=hi.x; f[5]=hi.y; f[6]=hi.z; f[7]=hi.w;
            } else {
                #pragma unroll
                for (int j = 0; j < 8; ++j)
                    f[j] = (rok && gk + j < FIN) ? Ab[j] : 0.f;
            }
            #pragma unroll
            for (int j = 0; j < 8; ++j) av[j] = f2bf(f[j]);
            *(su16x8*)&Al[srow * 32 + 8 * (sch ^ ((srow >> 1) & 3))] = av;
        }
        {
            const unsigned short* Bb = Bct + (size_t)(n0 + t) * K + k0;
            #pragma unroll
            for (int q = 0; q < 4; ++q)
                *(su16x8*)&Bpl[q][t * 8] = *(const su16x8*)(Bb + q * 8);
        }
        __syncthreads();
        bf16x8 af[4], bfr[8];
        #pragma unroll
        for (int m = 0; m < 4; ++m) {
            int r  = wm * 64 + m * 16 + (lane & 15);
            int kq = lane >> 4;
            af[m] = *(const bf16x8*)&Al[r * 32 + 8 * (kq ^ ((r >> 1) & 3))];
        }
        #pragma unroll
        for (int n = 0; n < 8; ++n) {
            int c = wn * 128 + n * 16 + (lane & 15);
            bfr[n] = *(const bf16x8*)&Bpl[lane >> 4][c * 8];
        }
        #pragma unroll
        for (int m = 0; m < 4; ++m)
            #pragma unroll
            for (int n = 0; n < 8; ++n)
                acc[m][n] = __builtin_amdgcn_mfma_f32_16x16x32_bf16(af[m], bfr[n], acc[m][n], 0, 0, 0);
    }

    #pragma unroll
    for (int m = 0; m < 4; ++m) {
        int rb = m0 + wm * 64 + m * 16 + (lane >> 4) * 4;
        #pragma unroll
        for (int n = 0; n < 8; ++n) {
            int c = n0 + wn * 128 + n * 16 + (lane & 15);
            #pragma unroll
            for (int j = 0; j < 4; ++j) {
                int r = rb + j;
                if (r < M) U[(size_t)r * 1024 + c] = f2bf(acc[m][n][j]);
            }
        }
    }
}

// ---------------- GEMMH: U[:, ooff..+512) = A @ Bct, bf16 A (stride 1024), K=512 ------
// 2-phase double-buffered global_load_lds pipeline, one barrier per k-tile.
// In-place safe: block reads only its own 128 rows; all A loads precede final barrier.
__global__ __launch_bounds__(512, 1)
void k_gemmh(const unsigned short* __restrict__ A, const unsigned short* __restrict__ Bct,
             unsigned short* __restrict__ U, int ooff, int M) {
    constexpr int KT = HID / 32;                  // 16
    __shared__ unsigned short Al[2][128 * 32];    // 16 KB
    __shared__ unsigned short Bl[2][4][HID * 8];  // 64 KB

    const int t    = threadIdx.x;
    const int lane = t & 63;
    const int wv   = t >> 6;
    const int wm   = wv >> 2, wn = wv & 3;
    const int m0   = blockIdx.x * 128;

    const int srow = t >> 2;
    const int gch  = ((t & 3) ^ ((srow >> 1) & 3)) * 8;  // inverse source swizzle
    const unsigned short* Ab = A + (size_t)(m0 + srow) * 1024 + gch;
    const bool rok = (m0 + srow) < M;
    const unsigned short* Bb = Bct + (size_t)t * HID;

    f32x4 acc[4][8];
    #pragma unroll
    for (int m = 0; m < 4; ++m)
        #pragma unroll
        for (int n = 0; n < 8; ++n)
            acc[m][n] = (f32x4){0.f, 0.f, 0.f, 0.f};

    // prologue: stage tile 0 into buf 0
    if (rok) gl_lds16(Ab, &Al[0][t * 8]);
    #pragma unroll
    for (int q = 0; q < 4; ++q) gl_lds16(Bb + q * 8, &Bl[0][q][t * 8]);
    __syncthreads();

    int cur = 0;
    for (int kt = 0; kt < KT; ++kt) {
        if (kt + 1 < KT) {  // prefetch next tile into other buffer (overlaps MFMA)
            const int k0 = (kt + 1) * 32;
            if (rok) gl_lds16(Ab + k0, &Al[cur ^ 1][t * 8]);
            #pragma unroll
            for (int q = 0; q < 4; ++q)
                gl_lds16(Bb + k0 + q * 8, &Bl[cur ^ 1][q][t * 8]);
        }
        bf16x8 af[4], bfr[8];
        #pragma unroll
        for (int m = 0; m < 4; ++m) {
            int r  = wm * 64 + m * 16 + (lane & 15);
            int kq = lane >> 4;
            af[m] = *(const bf16x8*)&Al[cur][r * 32 + 8 * (kq ^ ((r >> 1) & 3))];
        }
        #pragma unroll
        for (int n = 0; n < 8; ++n) {
            int c = wn * 128 + n * 16 + (lane & 15);
            bfr[n] = *(const bf16x8*)&Bl[cur][lane >> 4][c * 8];
        }
        #pragma unroll
        for (int m = 0; m < 4; ++m)
            #pragma unroll
            for (int n = 0; n < 8; ++n)
                acc[m][n] = __builtin_amdgcn_mfma_f32_16x16x32_bf16(af[m], bfr[n], acc[m][n], 0, 0, 0);
        __syncthreads();   // drains prefetch (vmcnt) + LDS reads before buffer reuse
        cur ^= 1;
    }

    #pragma unroll
    for (int m = 0; m < 4; ++m) {
        int rb = m0 + wm * 64 + m * 16 + (lane >> 4) * 4;
        #pragma unroll
        for (int n = 0; n < 8; ++n) {
            int c = ooff + wn * 128 + n * 16 + (lane & 15);
            #pragma unroll
            for (int j = 0; j < 4; ++j) {
                int r = rb + j;
                if (r < M) U[(size_t)r * 1024 + c] = f2bf(acc[m][n][j]);
            }
        }
    }
}

// ---------------- aggr: U0[d] += sum_e w_e * U1[src_e]; optional fused bias+relu -------
template<int RELU>
__global__ void k_aggr(unsigned short* U, const int* __restrict__ rowptr,
                       const int* __restrict__ esrc, const int* __restrict__ deg,
                       const float* __restrict__ bias, int M) {
    int wid  = (blockIdx.x * 256 + threadIdx.x) >> 6;
    int lane = threadIdx.x & 63;
    if (wid >= M) return;
    int e0 = rowptr[wid], e1 = rowptr[wid + 1];
    if (RELU == 0 && e0 == e1) return;   // row unchanged

    unsigned short* u0 = U + (size_t)wid * 1024 + lane * 8;
    uint4 v0 = *(const uint4*)u0;
    unsigned int a0[4] = {v0.x, v0.y, v0.z, v0.w};
    float acc[8];
    #pragma unroll
    for (int i = 0; i < 4; ++i) {
        acc[2 * i]     = bf2f((unsigned short)(a0[i] & 0xffffu));
        acc[2 * i + 1] = bf2f((unsigned short)(a0[i] >> 16));
    }

    if (e0 < e1) {
        int dd = deg[wid];
        float dr = dd > 0 ? rsqrtf((float)dd) : 0.f;
        for (int e = e0; e < e1; ++e) {
            int s = esrc[e];
            float we = -dr * rsqrtf((float)deg[s]);
            const uint4 v = *(const uint4*)(U + (size_t)s * 1024 + 512 + lane * 8);
            unsigned int uu[4] = {v.x, v.y, v.z, v.w};
            #pragma unroll
            for (int i = 0; i < 4; ++i) {
                acc[2 * i]     += we * bf2f((unsigned short)(uu[i] & 0xffffu));
                acc[2 * i + 1] += we * bf2f((unsigned short)(uu[i] >> 16));
            }
        }
    }

    if (RELU) {  // h = relu(acc + bias): materialize activation directly
        float4 c0 = *(const float4*)(bias + lane * 8);
        float4 c1 = *(const float4*)(bias + lane * 8 + 4);
        float bb[8] = {c0.x,c0.y,c0.z,c0.w,c1.x,c1.y,c1.z,c1.w};
        #pragma unroll
        for (int i = 0; i < 8; ++i) {
            float f = acc[i] + bb[i];
            acc[i] = f > 0.f ? f : 0.f;
        }
    }
    uint4 w4;
    unsigned int* wo = (unsigned int*)&w4;
    #pragma unroll
    for (int i = 0; i < 4; ++i)
        wo[i] = ((unsigned int)f2bf(acc[2 * i + 1]) << 16) | (unsigned int)f2bf(acc[2 * i]);
    *(uint4*)u0 = w4;
}

// ---------------- final: out = relu(U0 + b2) @ Wl + bl ----------------
__global__ void k_final(const unsigned short* __restrict__ U, const float* __restrict__ b2,
                        const float* __restrict__ Wl, const float* __restrict__ bl,
                        float* __restrict__ out, int M) {
    int wid  = (blockIdx.x * 256 + threadIdx.x) >> 6;
    int lane = threadIdx.x & 63;
    if (wid >= M) return;
    const uint4 v = *(const uint4*)(U + (size_t)wid * 1024 + lane * 8);
    float4 c0 = *(const float4*)(b2 + lane * 8);
    float4 c1 = *(const float4*)(b2 + lane * 8 + 4);
    float bb[8] = {c0.x,c0.y,c0.z,c0.w,c1.x,c1.y,c1.z,c1.w};
    const float4* Wp = reinterpret_cast<const float4*>(Wl + lane * 16);
    float4 w0 = Wp[0], w1 = Wp[1], w2 = Wp[2], w3 = Wp[3];
    float wv[16] = {w0.x, w0.y, w0.z, w0.w, w1.x, w1.y, w1.z, w1.w,
                    w2.x, w2.y, w2.z, w2.w, w3.x, w3.y, w3.z, w3.w};
    unsigned int uu[4] = {v.x, v.y, v.z, v.w};
    float s0 = 0.f, s1 = 0.f;
    #pragma unroll
    for (int j = 0; j < 4; ++j) {
        float f0 = bf2f((unsigned short)(uu[j] & 0xffffu)) + bb[2 * j];
        float f1 = bf2f((unsigned short)(uu[j] >> 16))     + bb[2 * j + 1];
        f0 = f0 > 0.f ? f0 : 0.f;
        f1 = f1 > 0.f ? f1 : 0.f;
        s0 += f0 * wv[4 * j + 0];
        s1 += f0 * wv[4 * j + 1];
        s0 += f1 * wv[4 * j + 2];
        s1 += f1 * wv[4 * j + 3];
    }
    #pragma unroll
    for (int off = 32; off; off >>= 1) {
        s0 += __shfl_xor(s0, off, 64);
        s1 += __shfl_xor(s1, off, 64);
    }
    if (lane == 0) {
        out[2 * (size_t)wid]     = s0 + bl[0];
        out[2 * (size_t)wid + 1] = s1 + bl[1];
    }
}

extern "C" void kernel_launch(void* const* d_in, const int* in_sizes, int n_in,
                              void* d_out, int out_size, void* d_ws, size_t ws_size,
                              hipStream_t stream) {
    const float* x    = (const float*)d_in[0];
    const int*   ei   = (const int*)d_in[1];
    const float* W1_0 = (const float*)d_in[2];
    const float* W1_1 = (const float*)d_in[3];
    const float* b1   = (const float*)d_in[4];
    const float* W2_0 = (const float*)d_in[5];
    const float* W2_1 = (const float*)d_in[6];
    const float* b2   = (const float*)d_in[7];
    const float* Wl   = (const float*)d_in[8];
    const float* bl   = (const float*)d_in[9];
    const int* src = ei;
    const int* dst = ei + NEDGES;
    float* out = (float*)d_out;

    char* ws = (char*)d_ws;
    size_t off = 0;
    auto alloc = [&](size_t bytes) -> void* {
        void* p = ws + off;
        off += (bytes + 255) & ~(size_t)255;
        return p;
    };
    int*            deg    = (int*)alloc((size_t)NNODES * 4);
    int*            cnt    = (int*)alloc((size_t)NNODES * 4);
    int*            rowptr = (int*)alloc((size_t)(NNODES + 1) * 4);
    int*            btot   = (int*)alloc((size_t)NB * 4);
    unsigned short* Bct1   = (unsigned short*)alloc((size_t)1024 * K1P * 2);
    unsigned short* Bct2   = (unsigned short*)alloc((size_t)1024 * HID * 2);
    unsigned short* U      = (unsigned short*)alloc((size_t)NNODES * 1024 * 2);
    int* esrc;
    if (off + (size_t)NEDGES * 4 <= ws_size) esrc = (int*)alloc((size_t)NEDGES * 4);
    else                                     esrc = (int*)d_out;  // dead until k_final

    hipMemsetAsync(deg, 0, (size_t)NNODES * 4, stream);
    hipMemsetAsync(cnt, 0, (size_t)NNODES * 4, stream);

    // CSR build + degrees
    k_deg    <<<(NEDGES + 255) / 256, 256, 0, stream>>>(src, dst, deg, cnt, NEDGES);
    k_scan1  <<<NB, 256, 0, stream>>>(cnt, btot, NNODES);
    k_scan2  <<<1, 1024, 0, stream>>>(btot, NB);
    k_scan3  <<<NB, 256, 0, stream>>>(cnt, btot, rowptr, NNODES, NEDGES);
    k_scatter<<<(NEDGES + 255) / 256, 256, 0, stream>>>(src, dst, rowptr, cnt, esrc, NEDGES);

    k_buildB1<<<(1024 * K1P + 255) / 256, 256, 0, stream>>>(W1_0, W1_1, Bct1);
    k_buildB2<<<(1024 * HID + 255) / 256, 256, 0, stream>>>(W2_0, W2_1, Bct2);

    const int nblk = (NNODES + 127) / 128;

    // layer 1: U = x @ [W1_0|W1_1]; aggr folds prop + bias + relu -> U0 = h1
    k_gemm0<<<dim3(2, nblk), 512, 0, stream>>>(x, Bct1, U, NNODES);
    k_aggr<1><<<NNODES / 4, 256, 0, stream>>>(U, rowptr, esrc, deg, b1, NNODES);

    // layer 2: U1 <- h1@W2_1, then U0 <- h1@W2_0 (in-place); aggr leaves raw pre-act
    k_gemmh<<<nblk, 512, 0, stream>>>(U, Bct2 + (size_t)HID * HID, U, 512, NNODES);
    k_gemmh<<<nblk, 512, 0, stream>>>(U, Bct2, U, 0, NNODES);
    k_aggr<0><<<NNODES / 4, 256, 0, stream>>>(U, rowptr, esrc, deg, nullptr, NNODES);

    // out = relu(U0 + b2) @ Wl + bl
    k_final<<<NNODES / 4, 256, 0, stream>>>(U, b2, Wl, bl, out, NNODES);
}